// Round 5
// baseline (162.440 us; speedup 1.0000x reference)
//
#include <hip/hip_runtime.h>
#include <hip/hip_bf16.h>
#include <stdint.h>

// B=2, N=2048, DIM=1024, HEADS=8, DIM_HEAD=64, INNER=512
// Round 5: barrier-free flash. gemm_qkv writes Q,K frag-major [row][d] and
// V frag-major [d][key] per (b,h); flash loads all MFMA operands (except P)
// straight from L2 with coalesced dwordx4, LDS only for the per-wave P
// round-trip -> zero __syncthreads in flash. Double-buffered K/V reg prefetch.

#define B_ 2
#define N_ 2048
#define DIM_ 1024
#define DH_ 64
#define INNER_ 512
#define ROWS_ 4096
#define POSTRIDE 2097152   // 16*2048*64 floats per split
#define BHSTRIDE 131072    // 2048*64 elems per (b,h) for qf/kf/vf

// q scale 1/8 (=DH^-0.5) * log2(e), folded into wq cast; kernel uses exp2.
#define QSCALE 0.18033688011112042f

typedef __bf16 bf16x8 __attribute__((ext_vector_type(8)));
typedef float floatx4 __attribute__((ext_vector_type(4)));

#if __has_builtin(__builtin_amdgcn_exp2f)
#define EXP2(x) __builtin_amdgcn_exp2f(x)
#else
#define EXP2(x) exp2f(x)
#endif

__device__ __forceinline__ ushort f2bf(float f) {
    union { float f; uint32_t u; } v; v.f = f;
    uint32_t u = v.u;
    u += 0x7fffu + ((u >> 16) & 1u);   // RNE
    return (ushort)(u >> 16);
}
__device__ __forceinline__ uint32_t pkbf(float a, float b) {
    return (uint32_t)f2bf(a) | ((uint32_t)f2bf(b) << 16);
}
// frag-major element offset: lane l of a wave holds M=16*T+(l&15),
// k = 32*kc + 8*(l>>4) + j  (j=0..7). nkc = K/32.
__device__ __forceinline__ size_t frag_off(int m, int k, int nkc) {
    return ((size_t)((m >> 4) * nkc + (k >> 5)) * 64 +
            (size_t)((m & 15) | (((k >> 3) & 3) << 4))) * 8 + (k & 7);
}

// ---------------------------------------------------------------------------
// K1: fused setup. blocks 0..255: partial column stats (seq axis).
// blocks 256..2303: weight cast into frag-major layouts (wqkv_f K=1024,
// wo_f K=512) via 32x32 LDS tiles.
__global__ __launch_bounds__(256) void setup_fused(
    const float* __restrict__ x, float* __restrict__ ps, float* __restrict__ pq,
    const float* __restrict__ wq, const float* __restrict__ wkv,
    const float* __restrict__ wo, ushort* __restrict__ wqkv_f,
    ushort* __restrict__ wo_f) {
    __shared__ float tile[32][33];
    int bid = blockIdx.x;
    if (bid < 256) {
        int gd = (bid & 7) * 256 + threadIdx.x;   // b*1024 + c
        int ch = bid >> 3;                        // 0..31
        int b = gd >> 10;
        const float* p = x + (size_t)(b * N_ + ch * 64) * DIM_ + (gd & 1023);
        float s = 0.f, q = 0.f;
#pragma unroll 4
        for (int n = 0; n < 64; ++n) { float v = p[(size_t)n * DIM_]; s += v; q += v * v; }
        ps[ch * 2048 + gd] = s;
        pq[ch * 2048 + gd] = q;
        return;
    }
    int t = bid - 256;
    const float* src; ushort* dst; int C, K, k0, ncol0, nglob0; float scale;
    if (t < 512) {          // wq: (1024 k x 512 n), 32x16 tiles
        int kt = t >> 4, nt = t & 15;
        src = wq; dst = wqkv_f; C = 512; K = 1024; scale = QSCALE;
        k0 = kt * 32; ncol0 = nt * 32; nglob0 = ncol0;
    } else if (t < 1536) {  // wkv: (1024 k x 1024 n) -> n-global 512..1535
        int u = t - 512; int kt = u >> 5, nt = u & 31;
        src = wkv; dst = wqkv_f; C = 1024; K = 1024; scale = 1.f;
        k0 = kt * 32; ncol0 = nt * 32; nglob0 = 512 + ncol0;
    } else {                // wo: (512 k x 1024 n)
        int u = t - 1536; int kt = u >> 5, nt = u & 31;
        src = wo; dst = wo_f; C = 1024; K = 512; scale = 1.f;
        k0 = kt * 32; ncol0 = nt * 32; nglob0 = ncol0;
    }
    int ti = threadIdx.x >> 5, tj = threadIdx.x & 31;
#pragma unroll
    for (int p = 0; p < 4; ++p)
        tile[ti + 8 * p][tj] = src[(size_t)(k0 + ti + 8 * p) * C + ncol0 + tj] * scale;
    __syncthreads();
    if (threadIdx.x < 128) {
        int nl = threadIdx.x & 31, kc8 = threadIdx.x >> 5;   // 0..3
        union { ushort us[8]; uint4 v; } u;
#pragma unroll
        for (int ii = 0; ii < 8; ++ii) u.us[ii] = f2bf(tile[kc8 * 8 + ii][nl]);
        *(uint4*)&dst[frag_off(nglob0 + nl, k0 + kc8 * 8, K >> 5)] = u.v;
    }
}

// ---------------------------------------------------------------------------
// K2: fused finalize + normalize + cast to frag-major xn. grid 512, block 256.
__global__ __launch_bounds__(256) void finalize_norm(
    const float* __restrict__ ps, const float* __restrict__ pq,
    const float* __restrict__ x, const float* __restrict__ g,
    ushort* __restrict__ xnf) {
    __shared__ float s4[4][64], q4[4][64], aa[64], bb[64];
    int t = threadIdx.x;
    int b = blockIdx.x >> 8, slab = (blockIdx.x >> 4) & 15, nch = blockIdx.x & 15;
    int c0 = slab * 64;
    {
        int c = t & 63, grp = t >> 6;
        float s = 0.f, q = 0.f;
#pragma unroll
        for (int ch = 0; ch < 8; ++ch) {
            int o = (grp * 8 + ch) * 2048 + b * 1024 + c0 + c;
            s += ps[o]; q += pq[o];
        }
        s4[grp][c] = s; q4[grp][c] = q;
    }
    __syncthreads();
    if (t < 64) {
        float s = s4[0][t] + s4[1][t] + s4[2][t] + s4[3][t];
        float q = q4[0][t] + q4[1][t] + q4[2][t] + q4[3][t];
        float mean = s * (1.f / N_);
        float var = q * (1.f / N_) - mean * mean;
        float rstd = rsqrtf(var + 1e-5f);
        float a = rstd * g[c0 + t];
        aa[t] = a; bb[t] = -mean * a;
    }
    __syncthreads();
    int c4 = (t & 15) * 4, ro = t >> 4;
#pragma unroll
    for (int it = 0; it < 8; ++it) {
        int r = nch * 128 + it * 16 + ro;
        int m = b * 2048 + r;
        float4 xv = *(const float4*)&x[(size_t)m * DIM_ + c0 + c4];
        float v0 = xv.x * aa[c4 + 0] + bb[c4 + 0];
        float v1 = xv.y * aa[c4 + 1] + bb[c4 + 1];
        float v2 = xv.z * aa[c4 + 2] + bb[c4 + 2];
        float v3 = xv.w * aa[c4 + 3] + bb[c4 + 3];
        uint2 u; u.x = pkbf(v0, v1); u.y = pkbf(v2, v3);
        *(uint2*)&xnf[frag_off(m, c0 + c4, 32)] = u;
    }
}

// ---------------------------------------------------------------------------
// LDS-free GEMM core: wave tile 64x64 as 4x4 MFMA 16x16x32, both operands
// frag-major in global, 2-stage register pipeline, no barriers.
template <int NKC>
__device__ __forceinline__ void gemm_core(
    const ushort* __restrict__ pA, const ushort* __restrict__ pB,
    floatx4 (&acc)[4][4]) {
    constexpr int TS = NKC * 512;     // m-tile stride (elems)
    bf16x8 a0[4], b0[4], a1[4], b1[4];
#pragma unroll
    for (int i = 0; i < 4; ++i) {
        a0[i] = *(const bf16x8*)(pA + (size_t)i * TS);
        b0[i] = *(const bf16x8*)(pB + (size_t)i * TS);
    }
    for (int kc = 0; kc < NKC; kc += 2) {
#pragma unroll
        for (int i = 0; i < 4; ++i) {
            a1[i] = *(const bf16x8*)(pA + (size_t)i * TS + (size_t)(kc + 1) * 512);
            b1[i] = *(const bf16x8*)(pB + (size_t)i * TS + (size_t)(kc + 1) * 512);
        }
#pragma unroll
        for (int mi = 0; mi < 4; ++mi)
#pragma unroll
            for (int ni = 0; ni < 4; ++ni)
                acc[mi][ni] = __builtin_amdgcn_mfma_f32_16x16x32_bf16(
                    a0[mi], b0[ni], acc[mi][ni], 0, 0, 0);
        if (kc + 2 < NKC) {
#pragma unroll
            for (int i = 0; i < 4; ++i) {
                a0[i] = *(const bf16x8*)(pA + (size_t)i * TS + (size_t)(kc + 2) * 512);
                b0[i] = *(const bf16x8*)(pB + (size_t)i * TS + (size_t)(kc + 2) * 512);
            }
        }
#pragma unroll
        for (int mi = 0; mi < 4; ++mi)
#pragma unroll
            for (int ni = 0; ni < 4; ++ni)
                acc[mi][ni] = __builtin_amdgcn_mfma_f32_16x16x32_bf16(
                    a1[mi], b1[ni], acc[mi][ni], 0, 0, 0);
    }
}

// K3: qkv GEMM. grid (64, 12), block 128.
// by<8: Q|K -> qf/kf per-bh frag-major [row][d] (nkc=2).
// by>=8: V -> vf per-bh frag-major [d][key] (nkc=64), packed b64 stores.
__global__ __launch_bounds__(128) void gemm_qkv(
    const ushort* __restrict__ xnf, const ushort* __restrict__ wf,
    ushort* __restrict__ qf, ushort* __restrict__ kf, ushort* __restrict__ vf) {
    int tx = threadIdx.x, w = tx >> 6, l = tx & 63;
    int lr = l & 15, lq = l >> 4;
    int bx = blockIdx.x, by = blockIdx.y;
    const ushort* pA = xnf + (size_t)(bx * 4) * 32 * 512 + l * 8;
    const ushort* pB = wf + (size_t)(by * 8 + w * 4) * 32 * 512 + l * 8;
    floatx4 acc[4][4] = {};
    gemm_core<32>(pA, pB, acc);
    int col0 = by * 128 + w * 64;
    int bb2 = (bx * 64) >> 11;          // batch index (uniform per block)
    if (by < 8) {
        ushort* qkbase = (by < 4) ? qf : kf;
#pragma unroll
        for (int ni = 0; ni < 4; ++ni) {
            int col = col0 + 16 * ni + lr;
            int hh = (col >> 6) & 7, d = col & 63;
            ushort* base = qkbase + (size_t)(bb2 * 8 + hh) * BHSTRIDE
                           + (d >> 5) * 512 + ((d >> 3) & 3) * 128 + (d & 7)
                           + (4 * lq) * 8;
#pragma unroll
            for (int mi = 0; mi < 4; ++mi) {
                size_t o2 = (size_t)((bx * 4 + mi) & 127) * 1024;
#pragma unroll
                for (int reg = 0; reg < 4; ++reg)
                    base[o2 + reg * 8] = f2bf(acc[mi][ni][reg]);
            }
        }
    } else {
#pragma unroll
        for (int ni = 0; ni < 4; ++ni) {
            int cv = col0 - 1024 + 16 * ni + lr;
            int hh = cv >> 6, d = cv & 63;
            ushort* base = vf + (size_t)(bb2 * 8 + hh) * BHSTRIDE
                           + (d >> 4) * 32768 + (d & 15) * 8;
#pragma unroll
            for (int mi = 0; mi < 4; ++mi) {
                int nn = (bx * 64 + 16 * mi + 4 * lq) & 2047;
                uint2 u;
                u.x = pkbf(acc[mi][ni][0], acc[mi][ni][1]);
                u.y = pkbf(acc[mi][ni][2], acc[mi][ni][3]);
                *(uint2*)&base[(nn >> 5) * 512 + ((nn >> 3) & 3) * 128 + (nn & 7)] = u;
            }
        }
    }
}

// K6: out GEMM. grid (64, 8), block 128.
__global__ __launch_bounds__(128) void gemm_out(
    const ushort* __restrict__ af, const ushort* __restrict__ wf,
    float* __restrict__ out) {
    int tx = threadIdx.x, w = tx >> 6, l = tx & 63;
    int lr = l & 15, lq = l >> 4;
    int bx = blockIdx.x, by = blockIdx.y;
    const ushort* pA = af + (size_t)(bx * 4) * 16 * 512 + l * 8;
    const ushort* pB = wf + (size_t)(by * 8 + w * 4) * 16 * 512 + l * 8;
    floatx4 acc[4][4] = {};
    gemm_core<16>(pA, pB, acc);
    int col0 = by * 128 + w * 64;
#pragma unroll
    for (int mi = 0; mi < 4; ++mi)
#pragma unroll
        for (int ni = 0; ni < 4; ++ni) {
            int col = col0 + 16 * ni + lr;
#pragma unroll
            for (int reg = 0; reg < 4; ++reg) {
                int row = bx * 64 + 16 * mi + 4 * lq + reg;
                out[(size_t)row * 1024 + col] = acc[mi][ni][reg];
            }
        }
}

// ---------------------------------------------------------------------------
// K4: barrier-free split-KV flash. grid (16 qtiles-of-128, 16 bh, nsplit),
// block 256 = 4 independent waves x 32 q-rows. All MFMA operands except P
// load straight from frag-major global (L2); LDS = per-wave P only.
__global__ __launch_bounds__(256, 2) void flash_attn(
    const ushort* __restrict__ qf, const ushort* __restrict__ kf,
    const ushort* __restrict__ vf, float* __restrict__ po,
    float* __restrict__ pl, int nkt) {
    __shared__ __align__(16) ushort sP[4][32 * 72];

    const int tx = threadIdx.x;
    const int w = tx >> 6, l = tx & 63;
    const int lr = l & 15, lq = l >> 4;
    const int qt = blockIdx.x, bh = blockIdx.y, sp = blockIdx.z;
    const int qbase = qt * 128;
    const int kbase = sp * nkt * 64;

    const ushort* qfb = qf + (size_t)bh * BHSTRIDE + (size_t)(qbase + 32 * w) * 64 + l * 8;
    const ushort* kfb = kf + (size_t)bh * BHSTRIDE + (size_t)kbase * 64 + l * 8;
    const ushort* vfb = vf + (size_t)bh * BHSTRIDE + (size_t)kbase * 16 + l * 8;
    ushort* sPw = &sP[w][0];

    // Q frags (B operand), resident for whole kernel
    bf16x8 bq[2][2];
#pragma unroll
    for (int qq = 0; qq < 2; ++qq)
#pragma unroll
        for (int s = 0; s < 2; ++s)
            bq[qq][s] = *(const bf16x8*)(qfb + qq * 1024 + s * 512);

    floatx4 o[2][4] = {};
    float lsum[2] = {0.f, 0.f};

    bf16x8 ak[2][8], bv[2][8];
    auto load_kv = [&](int kt, int buf) {
        const ushort* kp = kfb + (size_t)kt * 4096;   // kt*64 keys * 64 d
        const ushort* vp = vfb + (size_t)kt * 1024;   // kt*64 keys * 16
#pragma unroll
        for (int kk = 0; kk < 4; ++kk) {
            ak[buf][kk * 2 + 0] = *(const bf16x8*)(kp + kk * 1024);
            ak[buf][kk * 2 + 1] = *(const bf16x8*)(kp + kk * 1024 + 512);
        }
#pragma unroll
        for (int dt = 0; dt < 4; ++dt) {
            bv[buf][dt * 2 + 0] = *(const bf16x8*)(vp + dt * 32768);
            bv[buf][dt * 2 + 1] = *(const bf16x8*)(vp + dt * 32768 + 512);
        }
    };
    auto compute = [&](int buf) {
        // S^T = K . Q^T : c[kk][qq], rows=keys, cols=q
        floatx4 c[4][2] = {};
#pragma unroll
        for (int s = 0; s < 2; ++s)
#pragma unroll
            for (int kk = 0; kk < 4; ++kk)
#pragma unroll
                for (int qq = 0; qq < 2; ++qq)
                    c[kk][qq] = __builtin_amdgcn_mfma_f32_16x16x32_bf16(
                        ak[buf][kk * 2 + s], bq[qq][s], c[kk][qq], 0, 0, 0);
        // exp2, row-sums, pack consecutive-key pairs -> per-wave P in LDS
#pragma unroll
        for (int kk = 0; kk < 4; ++kk)
#pragma unroll
            for (int qq = 0; qq < 2; ++qq) {
                float e0 = EXP2(c[kk][qq][0]);
                float e1 = EXP2(c[kk][qq][1]);
                float e2 = EXP2(c[kk][qq][2]);
                float e3 = EXP2(c[kk][qq][3]);
                lsum[qq] += (e0 + e1) + (e2 + e3);
                uint2 u; u.x = pkbf(e0, e1); u.y = pkbf(e2, e3);
                *(uint2*)&sPw[(16 * qq + lr) * 72 + 16 * kk + 4 * lq] = u;
            }
        // O += P @ V (in-wave LDS round-trip; lgkmcnt ordering by compiler)
#pragma unroll
        for (int s = 0; s < 2; ++s) {
            bf16x8 ap[2];
#pragma unroll
            for (int mi = 0; mi < 2; ++mi)
                ap[mi] = *(const bf16x8*)&sPw[(16 * mi + lr) * 72 + 32 * s + 8 * lq];
#pragma unroll
            for (int mi = 0; mi < 2; ++mi)
#pragma unroll
                for (int dt = 0; dt < 4; ++dt)
                    o[mi][dt] = __builtin_amdgcn_mfma_f32_16x16x32_bf16(
                        ap[mi], bv[buf][dt * 2 + s], o[mi][dt], 0, 0, 0);
        }
    };

    load_kv(0, 0);
    int kt = 0;
    for (; kt + 2 <= nkt; kt += 2) {
        load_kv(kt + 1, 1);
        compute(0);
        if (kt + 2 < nkt) load_kv(kt + 2, 0);
        compute(1);
    }
    if (kt < nkt) compute(0);   // odd-nkt tail (unused for nsplit in {1,2,4})

#pragma unroll
    for (int qq = 0; qq < 2; ++qq) {
        lsum[qq] += __shfl_xor(lsum[qq], 16);
        lsum[qq] += __shfl_xor(lsum[qq], 32);
    }
    float* pob = po + (size_t)sp * POSTRIDE;
    if (lq == 0) {
#pragma unroll
        for (int qq = 0; qq < 2; ++qq)
            pl[((size_t)sp * 16 + bh) * N_ + qbase + 32 * w + 16 * qq + lr] = lsum[qq];
    }
    const size_t obase = (size_t)bh * N_;
#pragma unroll
    for (int mi = 0; mi < 2; ++mi)
#pragma unroll
        for (int dt = 0; dt < 4; ++dt)
#pragma unroll
            for (int reg = 0; reg < 4; ++reg) {
                int row = qbase + 32 * w + 16 * mi + 4 * lq + reg;
                pob[(obase + row) * DH_ + 16 * dt + lr] = o[mi][dt][reg];
            }
}

// K5: merge splits + normalize + cast; writes attn frag-major (K=512).
__global__ __launch_bounds__(256) void merge_attn(
    const float* __restrict__ po, const float* __restrict__ pl,
    ushort* __restrict__ attnf, int nsplit) {
    int idx = blockIdx.x * 256 + threadIdx.x;
    int d4 = (idx & 15) * 4;
    int h = (idx >> 4) & 7;
    int rowg = idx >> 7;
    int b = rowg >> 11, r = rowg & 2047;
    size_t pbase = ((size_t)b * 8 + h) * N_ + r;
    float4 acc = *(const float4*)&po[pbase * DH_ + d4];
    float lv = pl[pbase];
    for (int s = 1; s < nsplit; ++s) {
        float4 a1 = *(const float4*)&po[(size_t)s * POSTRIDE + pbase * DH_ + d4];
        acc.x += a1.x; acc.y += a1.y; acc.z += a1.z; acc.w += a1.w;
        lv += pl[((size_t)s * 16) * N_ + pbase];
    }
    float inv = 1.f / lv;
    uint2 u;
    u.x = pkbf(acc.x * inv, acc.y * inv);
    u.y = pkbf(acc.z * inv, acc.w * inv);
    *(uint2*)&attnf[frag_off(rowg, h * DH_ + d4, 16)] = u;
}

// ---------------------------------------------------------------------------
extern "C" void kernel_launch(void* const* d_in, const int* in_sizes, int n_in,
                              void* d_out, int out_size, void* d_ws, size_t ws_size,
                              hipStream_t stream) {
    const float* x   = (const float*)d_in[0];
    const float* g   = (const float*)d_in[1];
    const float* wq  = (const float*)d_in[2];
    const float* wkv = (const float*)d_in[3];
    const float* wo  = (const float*)d_in[4];
    float* out = (float*)d_out;

    char* ws = (char*)d_ws;
    float*  psum   = (float*)(ws + 0);          // 256K
    float*  psqr   = (float*)(ws + 262144);     // 256K
    ushort* xnf    = (ushort*)(ws + 524288);    // 8.39M frag-major K=1024
    ushort* wqkv_f = (ushort*)(ws + 8912896);   // 3.15M frag-major K=1024
    ushort* wo_f   = (ushort*)(ws + 12058624);  // 1.05M frag-major K=512
    ushort* qfb    = (ushort*)(ws + 13107200);  // 4.19M per-bh frag [row][d]
    ushort* kfb    = (ushort*)(ws + 17301504);  // 4.19M per-bh frag [row][d]
    ushort* vfb    = (ushort*)(ws + 21495808);  // 4.19M per-bh frag [d][key]
    ushort* attnf  = (ushort*)(ws + 25690112);  // 4.19M frag-major K=512
    float*  plb    = (float*)(ws + 29884416);   // 512K
    float*  pob    = (float*)(ws + 30408704);   // 4 x 8.39M -> end ~64M

    const int nsplit = (ws_size >= (size_t)66 * 1024 * 1024) ? 4
                     : (ws_size >= (size_t)48 * 1024 * 1024) ? 2 : 1;

    setup_fused<<<2304, 256, 0, stream>>>(x, psum, psqr, wq, wkv, wo, wqkv_f, wo_f);
    finalize_norm<<<512, 256, 0, stream>>>(psum, psqr, x, g, xnf);
    gemm_qkv<<<dim3(64, 12), 128, 0, stream>>>(xnf, wqkv_f, qfb, kfb, vfb);
    flash_attn<<<dim3(16, 16, nsplit), 256, 0, stream>>>(qfb, kfb, vfb, pob, plb, 32 / nsplit);
    merge_attn<<<2048, 256, 0, stream>>>(pob, plb, attnf, nsplit);
    gemm_out<<<dim3(64, 8), 128, 0, stream>>>(attnf, wo_f, out);
}